// Round 5
// baseline (153.107 us; speedup 1.0000x reference)
//
#include <hip/hip_runtime.h>

typedef _Float16 half_t;
typedef __attribute__((ext_vector_type(8))) _Float16 h8;
typedef __attribute__((ext_vector_type(2))) _Float16 h2v;
typedef __attribute__((ext_vector_type(4))) float f4;
typedef __attribute__((ext_vector_type(2))) float f2v;

// fp32 -> fp16 with inf/NaN killing (fmaxf/fminf return the non-NaN operand).
__device__ __forceinline__ half_t to_h(float v) {
    v = fminf(fmaxf(v, -60000.f), 60000.f);
    return (half_t)v;
}

// ---------------- pack kernel: bilaterally-coalesced fp32 -> fp16 MFMA-B frags ----------
// ws layout (half elements):
//   w1p: [0, 524288)          [kk=64][nt=16][lane=64][j=8]
//   w2p: [524288, 557056)     [kk=8][nt=8][64][8]
//   swp: [557056, 622592)     [kk=16][nt=8][64][8]
//   cwB: [622592, 632832)     [k5=5][nt=4][lane=64][j=8]  conv B-frags, taps 26..31 = 0
__global__ void pack_k(const float* __restrict__ w1, const float* __restrict__ w2,
                       const float* __restrict__ sw, const float* __restrict__ cw,
                       half_t* __restrict__ wsH) {
    int i = blockIdx.x * 256 + threadIdx.x;
    if (i < 65536) {                        // w1 [2048][256]: 65536 h8 jobs
        int L = i & 63, nt = (i >> 6) & 15, kk = i >> 10;
        int k0 = kk * 32 + ((L >> 4) << 3), n = (nt << 4) + (L & 15);
        h8 v;
#pragma unroll
        for (int j = 0; j < 8; j++) v[j] = to_h(w1[(k0 + j) * 256 + n]);
        *(h8*)(wsH + ((((kk * 16 + nt) * 64 + L)) << 3)) = v;
    } else if (i < 69632) {                 // w2 [256][128]: 4096 jobs
        int o = i - 65536;
        int L = o & 63, nt = (o >> 6) & 7, kk = o >> 9;
        int k0 = kk * 32 + ((L >> 4) << 3), n = (nt << 4) + (L & 15);
        h8 v;
#pragma unroll
        for (int j = 0; j < 8; j++) v[j] = to_h(w2[(k0 + j) * 128 + n]);
        *(h8*)(wsH + 524288 + ((((kk * 8 + nt) * 64 + L)) << 3)) = v;
    } else if (i < 77824) {                 // sw [512][128]: 8192 jobs
        int o = i - 69632;
        int L = o & 63, nt = (o >> 6) & 7, kk = o >> 9;
        int k0 = kk * 32 + ((L >> 4) << 3), n = (nt << 4) + (L & 15);
        h8 v;
#pragma unroll
        for (int j = 0; j < 8; j++) v[j] = to_h(sw[(k0 + j) * 128 + n]);
        *(h8*)(wsH + 557056 + ((((kk * 8 + nt) * 64 + L)) << 3)) = v;
    } else if (i < 79104) {                 // conv B-frags: 1280 h8 jobs
        int o = i - 77824;
        int L = o & 63, nt = (o >> 6) & 3, k5 = o >> 8;
        int n = nt * 16 + (L & 15);
        h8 v;
#pragma unroll
        for (int j = 0; j < 8; j++) {
            int kin = ((L >> 4) << 3) + j;                  // tap-channel within 32-group
            v[j] = (kin < 26) ? to_h(cw[(k5 * 26 + kin) * 64 + n]) : (half_t)0.f;
        }
        *(h8*)(wsH + 622592 + ((size_t)o << 3)) = v;
    }
}

// ---------------- main fused kernel ----------------
// OCCUPANCY RESTRUCTURE (R4 post-mortem): the 64-row design is register-bound at
// ~125 total regs -> 2 blocks/CU = 16 waves (occ 38%), with MfmaUtil 28 / VALU 40 /
// LDS-port ~50% — latency-bound. Halving the tile to 32 rows halves acc (32->16) and
// avr (32->16): total ~90 regs, capped to 85 by __launch_bounds__(512,6) -> 3 blocks/CU
// = 24 waves. Grid 1024 = 8 b x 128 t-tiles. Phase-2 inner structure (the empirical
// optimum: rolled masked loop, distance-1-pair B prefetch) is preserved verbatim —
// only the mt extent changes 4->2. P5 is the R0-proven LDS form (shuffle P5 = ds_bpermute
// = MORE LDS traffic, measured +3us in R4).
// Known costs: B-frag L2 traffic x2, conv work +33% (2.5% phase), 1024-on-768 packing tail.
#define XCS 72   // xcL row stride (halfs), 63 rows used, frame f <-> t = t0-31+f
#define XLS 32   // xLh row stride (halfs): 26 data + 6 zero-pad = conv MFMA A-layout
#define ALS 72   // aL row stride (halfs), 32 rows
#define Y1S 264  // y1L / hL row stride (halfs), 32 rows
#define SLS 68   // sLf row stride (floats)
#define HLS 20   // hidL row stride (floats)

#define MFMA16(a, b, c) __builtin_amdgcn_mfma_f32_16x16x32_f16(a, b, c, 0, 0, 0)

__global__ __launch_bounds__(512, 6) void beat_main(
    const float* __restrict__ x,
    const float* __restrict__ conv_b,
    const float* __restrict__ se_w1, const float* __restrict__ se_b1,
    const float* __restrict__ se_w2, const float* __restrict__ se_b2,
    const float* __restrict__ b1, const float* __restrict__ b2,
    const float* __restrict__ sb,
    const float* __restrict__ wo, const float* __restrict__ bo,
    const half_t* __restrict__ w1p, const half_t* __restrict__ w2p,
    const half_t* __restrict__ swp, const half_t* __restrict__ cwB,
    float* __restrict__ out) {

    __shared__ __align__(16) char smem[32768];
    half_t* xcL = (half_t*)smem;             // 64*72*2 = 9216 (rows 0..62 used)
    half_t* aL  = (half_t*)(smem + 9216);    // 32*72*2 = 4608 -> 13824
    char*   U   = smem + 13824;              // 16896-byte phase union
    half_t* xLh = (half_t*)U;                // phase0: 68*32 halfs = 4352
    float*  sLf = (float*)U;                 // phase1: 32*68 floats = 8704
    float*  hidL= (float*)(U + 8704);        // phase1: 32*20 floats = 2560
    half_t* y1L = (half_t*)U;                // phase2+: 32*264 halfs = 16896
    float*  woL = (float*)(smem + 30720);    // 512 floats -> 32768

    const int tid = threadIdx.x;
    const int bi = blockIdx.x;
    const int b = bi >> 7;
    const int t0 = (bi & 127) << 5;
    const int lane = tid & 63, wv = tid >> 6;     // wv in 0..7
    const int quad = lane >> 4, rl = lane & 15;

    // ---- phase 0a: stage x (fp16 pairs, rows zero-padded to 32) + wo ----
    if (tid < 256) ((f2v*)woL)[tid] = ((const f2v*)wo)[tid];   // 512 floats
    for (int idx = tid; idx < 68 * 13; idx += 512) {
        int fi = idx / 13, ip = idx - fi * 13;
        int tx = t0 - 35 + fi;
        h2v v;
        if (tx >= 0 && tx < 4096) {
            const float* xp = x + ((size_t)(b * 4096 + tx)) * 26 + 2 * ip;
            v[0] = to_h(xp[0]); v[1] = to_h(xp[1]);
        } else { v[0] = (_Float16)0.f; v[1] = (_Float16)0.f; }
        *(h2v*)(xLh + fi * XLS + 2 * ip) = v;
    }
    for (int idx = tid; idx < 68 * 3; idx += 512) {            // zero pad halfs 26..31
        int fi = idx / 3, p = idx - fi * 3;
        h2v z; z[0] = (_Float16)0.f; z[1] = (_Float16)0.f;
        *(h2v*)(xLh + fi * XLS + 26 + 2 * p) = z;
    }
    __syncthreads();

    // ---- phase 0b: conv as MFMA: xc = relu(win(x) @ cw + b), M=64(63) N=64 K=160 ----
    // 16 units (rb 0..3 x nt 0..3), 2 per wave; 5 MFMAs each (k5 = tap row).
    {
        const h8* cwv = (const h8*)cwB;        // frag(k5,nt) = cwv[(k5*4+nt)*64 + lane]
#pragma unroll
        for (int s = 0; s < 2; s++) {
            int u = wv + 8 * s;                // 0..15
            int rb = u >> 2, nt = u & 3;
            f4 acc;
#pragma unroll
            for (int r = 0; r < 4; r++) acc[r] = 0.f;
#pragma unroll
            for (int k5 = 0; k5 < 5; k5++) {
                h8 xv = *(const h8*)(xLh + (rb * 16 + rl + k5) * XLS + quad * 8);
                h8 bf = cwv[(k5 * 4 + nt) * 64 + lane];
                acc = MFMA16(xv, bf, acc);
            }
            int n = nt * 16 + rl;
            float bias = conv_b[n];
#pragma unroll
            for (int r = 0; r < 4; r++) {
                int m = rb * 16 + quad * 4 + r;
                if (m < 63) {
                    int t = t0 - 31 + m;
                    float v = (t >= 0) ? fmaxf(acc[r] + bias, 0.f) : 0.f;
                    xcL[m * XCS + n] = to_h(v);
                }
            }
        }
    }
    __syncthreads();

    // ---- phase 1a: window means s[m][c]; thread = (m, 8-channel group), h8 row reads ----
    if (tid < 256) {
        int m = tid >> 3, cg = tid & 7;
        const half_t* base = xcL + m * XCS + cg * 8;
        f4 a0, a1;
#pragma unroll
        for (int r = 0; r < 4; r++) { a0[r] = 0.f; a1[r] = 0.f; }
#pragma unroll
        for (int w = 0; w < 32; w++) {
            h8 v = *(const h8*)(base + w * XCS);
#pragma unroll
            for (int q = 0; q < 4; q++) { a0[q] += (float)v[q]; a1[q] += (float)v[4 + q]; }
        }
        float* sp = sLf + m * SLS + cg * 8;
        *(f4*)sp       = a0 * (1.f / 32.f);
        *(f4*)(sp + 4) = a1 * (1.f / 32.f);
    }
    __syncthreads();

    // ---- phase 1b: SE hidden = relu(s @ se_w1 + se_b1), 32 m x 16 h ----
    if (tid < 256) {
        int m = tid >> 3, hh = (tid & 7) * 2;
        float acc0 = se_b1[hh], acc1 = se_b1[hh + 1];
        for (int c = 0; c < 64; c++) {
            float sv = sLf[m * SLS + c];
            f2v wq = *(const f2v*)(se_w1 + c * 16 + hh);
            acc0 += sv * wq[0]; acc1 += sv * wq[1];
        }
        hidL[m * HLS + hh] = fmaxf(acc0, 0.f);
        hidL[m * HLS + hh + 1] = fmaxf(acc1, 0.f);
    }
    __syncthreads();

    // ---- phase 1c: a = sigmoid(hidden @ se_w2 + se_b2) -> aL (fp16) ----
    if (tid < 256) {
        int m = tid >> 3, c0 = (tid & 7) * 8;
        float av[8];
#pragma unroll
        for (int j = 0; j < 8; j++) av[j] = se_b2[c0 + j];
        for (int h = 0; h < 16; h++) {
            float hv = hidL[m * HLS + h];
            const f4* wv4 = (const f4*)(se_w2 + h * 64 + c0);
            f4 wq0 = wv4[0], wq1 = wv4[1];
#pragma unroll
            for (int j = 0; j < 4; j++) { av[j] += hv * wq0[j]; av[4 + j] += hv * wq1[j]; }
        }
#pragma unroll
        for (int j = 0; j < 8; j++) {
            float zz = fminf(fmaxf(av[j], -30.f), 30.f);
            float s = 1.f / (1.f + __expf(-zz));
            aL[m * ALS + c0 + j] = to_h(s);
        }
    }
    __syncthreads();

    // ---- gates into registers: avr[mt][half], rows mt*16+rl, channels half*32+quad*8 ----
    h8 avr[2][2];
#pragma unroll
    for (int mt = 0; mt < 2; mt++)
#pragma unroll
        for (int p = 0; p < 2; p++)
            avr[mt][p] = *(const h8*)(aL + (mt * 16 + rl) * ALS + p * 32 + quad * 8);

    // ---- phase 2: y1 = relu((a .* window) @ w1 + b1), M=32 K=2048 N=256 ----
    // wave wv: all 32 rows, cols wv*32..+32 (nt = wv*2+i). Prefetch distance 2 kk-steps.
    {
        f4 acc[2][2];
#pragma unroll
        for (int mt = 0; mt < 2; mt++)
#pragma unroll
            for (int i = 0; i < 2; i++)
#pragma unroll
                for (int r = 0; r < 4; r++) acc[mt][i][r] = 0.f;
        const h8* w1v = (const h8*)w1p;
        const int fb = wv * 2;
        h8 bA[2], bB[2], bC[2], bD[2];
#pragma unroll
        for (int i = 0; i < 2; i++) bA[i] = w1v[(fb + i) * 64 + lane];
#pragma unroll
        for (int i = 0; i < 2; i++) bB[i] = w1v[(16 + fb + i) * 64 + lane];
#pragma unroll 2
        for (int kk = 0; kk < 64; kk += 2) {
            const int k2 = (kk + 2) & 63, k3 = (kk + 3) & 63;  // wrap harmless on last iter
#pragma unroll
            for (int i = 0; i < 2; i++) bC[i] = w1v[(k2 * 16 + fb + i) * 64 + lane];
#pragma unroll
            for (int i = 0; i < 2; i++) bD[i] = w1v[(k3 * 16 + fb + i) * 64 + lane];
            const int wf = kk >> 1;
            {   // even kk: channels 0..31 -> avr[.][0]
                const int c0 = quad * 8;
#pragma unroll
                for (int mt = 0; mt < 2; mt++) {
                    int m = mt * 16 + rl;
                    h8 xv = *(const h8*)(xcL + (m + wf) * XCS + c0);
                    h8 af = xv * avr[mt][0];
                    acc[mt][0] = MFMA16(af, bA[0], acc[mt][0]);
                    acc[mt][1] = MFMA16(af, bA[1], acc[mt][1]);
                }
            }
            {   // odd kk: channels 32..63 -> avr[.][1]
                const int c0 = 32 + quad * 8;
#pragma unroll
                for (int mt = 0; mt < 2; mt++) {
                    int m = mt * 16 + rl;
                    h8 xv = *(const h8*)(xcL + (m + wf) * XCS + c0);
                    h8 af = xv * avr[mt][1];
                    acc[mt][0] = MFMA16(af, bB[0], acc[mt][0]);
                    acc[mt][1] = MFMA16(af, bB[1], acc[mt][1]);
                }
            }
#pragma unroll
            for (int i = 0; i < 2; i++) { bA[i] = bC[i]; bB[i] = bD[i]; }
        }
#pragma unroll
        for (int i = 0; i < 2; i++) {
            int n = wv * 32 + i * 16 + rl;
            float bb = b1[n];
#pragma unroll
            for (int mt = 0; mt < 2; mt++)
#pragma unroll
                for (int r = 0; r < 4; r++) {
                    int m = mt * 16 + quad * 4 + r;
                    y1L[m * Y1S + n] = to_h(fmaxf(acc[mt][i][r] + bb, 0.f));
                }
        }
    }
    __syncthreads();

    // ---- phase 3: h2 = relu(y1 @ w2 + b2), M=32 K=256 N=128; wave wv: cols wv*16..+16 ----
    f4 acc2[2];
#pragma unroll
    for (int mt = 0; mt < 2; mt++)
#pragma unroll
        for (int r = 0; r < 4; r++) acc2[mt][r] = 0.f;
    {
        const h8* w2v = (const h8*)w2p;
        h8 cf = w2v[wv * 64 + lane];
#pragma unroll 2
        for (int kk = 0; kk < 8; kk++) {
            int kn = (kk + 1) & 7;
            h8 nf = w2v[(kn * 8 + wv) * 64 + lane];
#pragma unroll
            for (int mt = 0; mt < 2; mt++) {
                h8 av = *(const h8*)(y1L + (mt * 16 + rl) * Y1S + kk * 32 + quad * 8);
                acc2[mt] = MFMA16(av, cf, acc2[mt]);
            }
            cf = nf;
        }
    }

    // ---- phase 4: h_short = relu((a .* window[-8:]) @ sw + sb), K=512 N=128 ----
    f4 accS[2];
#pragma unroll
    for (int mt = 0; mt < 2; mt++)
#pragma unroll
        for (int r = 0; r < 4; r++) accS[mt][r] = 0.f;
    {
        const h8* swv = (const h8*)swp;
        h8 cf = swv[wv * 64 + lane];
#pragma unroll 2
        for (int kk = 0; kk < 16; kk++) {
            int kn = (kk + 1) & 15;
            h8 nf = swv[(kn * 8 + wv) * 64 + lane];
            const int wf = 24 + (kk >> 1);
            const int c0 = ((kk & 1) << 5) + quad * 8;
#pragma unroll
            for (int mt = 0; mt < 2; mt++) {
                int m = mt * 16 + rl;
                h8 xv = *(const h8*)(xcL + (m + wf) * XCS + c0);
                h8 af = xv * avr[mt][kk & 1];
                accS[mt] = MFMA16(af, cf, accS[mt]);
            }
            cf = nf;
        }
    }
    __syncthreads();  // phase-3 reads of y1L done before overwrite

    // ---- phase 5a: hL[m][0:128]=relu(h2), hL[m][128:256]=relu(h_short) ----
    {
        int n = wv * 16 + rl;
        float bb2 = b2[n], bbs = sb[n];
#pragma unroll
        for (int mt = 0; mt < 2; mt++)
#pragma unroll
            for (int r = 0; r < 4; r++) {
                int m = mt * 16 + quad * 4 + r;
                y1L[m * Y1S + n]       = to_h(fmaxf(acc2[mt][r] + bb2, 0.f));
                y1L[m * Y1S + 128 + n] = to_h(fmaxf(accS[mt][r] + bbs, 0.f));
            }
    }
    __syncthreads();

    // ---- phase 5b: out = sigmoid(h @ wo + bo), 64 threads ----
    if (tid < 64) {
        int m = tid >> 1, o = tid & 1;
        float z = bo[o];
        const half_t* hrow = y1L + m * Y1S;
        for (int nb = 0; nb < 32; nb++) {
            h8 hv = *(const h8*)(hrow + nb * 8);
#pragma unroll
            for (int q = 0; q < 8; q++)
                z += (float)hv[q] * woL[(nb * 8 + q) * 2 + o];
        }
        z = fminf(fmaxf(z, -30.f), 30.f);
        float sg = 1.f / (1.f + __expf(-z));
        out[((size_t)(b * 4096 + t0 + m)) * 2 + o] = sg;
    }
}

extern "C" void kernel_launch(void* const* d_in, const int* in_sizes, int n_in,
                              void* d_out, int out_size, void* d_ws, size_t ws_size,
                              hipStream_t stream) {
    const float* x      = (const float*)d_in[0];
    const float* conv_w = (const float*)d_in[1];
    const float* conv_b = (const float*)d_in[2];
    const float* se_w1  = (const float*)d_in[3];
    const float* se_b1  = (const float*)d_in[4];
    const float* se_w2  = (const float*)d_in[5];
    const float* se_b2  = (const float*)d_in[6];
    const float* w1     = (const float*)d_in[7];
    const float* b1     = (const float*)d_in[8];
    const float* w2     = (const float*)d_in[9];
    const float* b2     = (const float*)d_in[10];
    const float* sw     = (const float*)d_in[11];
    const float* sb     = (const float*)d_in[12];
    const float* wo     = (const float*)d_in[13];
    const float* bo     = (const float*)d_in[14];
    half_t* wsH = (half_t*)d_ws;

    hipLaunchKernelGGL(pack_k, dim3(337), dim3(256), 0, stream, w1, w2, sw, conv_w, wsH);
    hipLaunchKernelGGL(beat_main, dim3(1024), dim3(512), 0, stream,
                       x, conv_b, se_w1, se_b1, se_w2, se_b2, b1, b2, sb, wo, bo,
                       wsH, wsH + 524288, wsH + 557056, wsH + 622592,
                       (float*)d_out);
}

// Round 6
// 147.195 us; speedup vs baseline: 1.0402x; 1.0402x over previous
//
#include <hip/hip_runtime.h>

typedef _Float16 half_t;
typedef __attribute__((ext_vector_type(8))) _Float16 h8;
typedef __attribute__((ext_vector_type(2))) _Float16 h2v;
typedef __attribute__((ext_vector_type(4))) float f4;
typedef __attribute__((ext_vector_type(2))) float f2v;

// fp32 -> fp16 with inf/NaN killing (fmaxf/fminf return the non-NaN operand).
__device__ __forceinline__ half_t to_h(float v) {
    v = fminf(fmaxf(v, -60000.f), 60000.f);
    return (half_t)v;
}

// ---------------- pack kernel: bilaterally-coalesced fp32 -> fp16 MFMA-B frags ----------
// ws layout (half elements):
//   w1p: [0, 524288)          [kk=64][nt=16][lane=64][j=8]
//   w2p: [524288, 557056)     [kk=8][nt=8][64][8]
//   swp: [557056, 622592)     [kk=16][nt=8][64][8]
//   cwB: [622592, 632832)     [k5=5][nt=4][lane=64][j=8]  conv B-frags, taps 26..31 = 0
__global__ void pack_k(const float* __restrict__ w1, const float* __restrict__ w2,
                       const float* __restrict__ sw, const float* __restrict__ cw,
                       half_t* __restrict__ wsH) {
    int i = blockIdx.x * 256 + threadIdx.x;
    if (i < 65536) {                        // w1 [2048][256]: 65536 h8 jobs
        int L = i & 63, nt = (i >> 6) & 15, kk = i >> 10;
        int k0 = kk * 32 + ((L >> 4) << 3), n = (nt << 4) + (L & 15);
        h8 v;
#pragma unroll
        for (int j = 0; j < 8; j++) v[j] = to_h(w1[(k0 + j) * 256 + n]);
        *(h8*)(wsH + ((((kk * 16 + nt) * 64 + L)) << 3)) = v;
    } else if (i < 69632) {                 // w2 [256][128]: 4096 jobs
        int o = i - 65536;
        int L = o & 63, nt = (o >> 6) & 7, kk = o >> 9;
        int k0 = kk * 32 + ((L >> 4) << 3), n = (nt << 4) + (L & 15);
        h8 v;
#pragma unroll
        for (int j = 0; j < 8; j++) v[j] = to_h(w2[(k0 + j) * 128 + n]);
        *(h8*)(wsH + 524288 + ((((kk * 8 + nt) * 64 + L)) << 3)) = v;
    } else if (i < 77824) {                 // sw [512][128]: 8192 jobs
        int o = i - 69632;
        int L = o & 63, nt = (o >> 6) & 7, kk = o >> 9;
        int k0 = kk * 32 + ((L >> 4) << 3), n = (nt << 4) + (L & 15);
        h8 v;
#pragma unroll
        for (int j = 0; j < 8; j++) v[j] = to_h(sw[(k0 + j) * 128 + n]);
        *(h8*)(wsH + 557056 + ((((kk * 8 + nt) * 64 + L)) << 3)) = v;
    } else if (i < 79104) {                 // conv B-frags: 1280 h8 jobs
        int o = i - 77824;
        int L = o & 63, nt = (o >> 6) & 3, k5 = o >> 8;
        int n = nt * 16 + (L & 15);
        h8 v;
#pragma unroll
        for (int j = 0; j < 8; j++) {
            int kin = ((L >> 4) << 3) + j;                  // tap-channel within 32-group
            v[j] = (kin < 26) ? to_h(cw[(k5 * 26 + kin) * 64 + n]) : (half_t)0.f;
        }
        *(h8*)(wsH + 622592 + ((size_t)o << 3)) = v;
    }
}

// ---------------- main fused kernel ----------------
// block = 512 thr (8 waves), one b and 64 consecutive t. Grid = 8*64 = 512.
// POST-MORTEM LEDGER:
//  R9/R11 (prev session): 32x32x16 restructure, full K unroll -> lost (stall / spills).
//  R2: P4-into-P2 fusion at cap-64 -> 15.6MB spills, +10us. R3: same at cap-128 ->
//      total regs crossed 128 -> 1 block/CU, +28us. ABANDONED.
//  R4: in-register P5 via __shfl_xor -> ds_bpermute = MORE LDS traffic, +3us. LDS P5 kept.
//  R5: 32-row half-tile, grid 1024 -> B-stream traffic x2, MFMA:B ratio halved, +13us.
// CURRENT CHANGE (R6): phase-2 wave split 8N -> 2M x 4N. All 8 waves previously read
// IDENTICAL A-fragments (8x redundant: 4096 ds_read_b128/CU ~= 20us LDS floor, + 8x
// redundant gate-muls). 2Mx4N halves both; MFMA count unchanged; B-traffic x2 (L2 has
// headroom). Phase 3/4/5 unchanged; phase-4 gates reloaded from intact aL after phase 3.
#define XCS 72   // xcL row stride (halfs), 95 rows, frame f <-> t = t0-31+f
#define XLS 32   // xLh row stride (halfs): 26 data + 6 zero-pad = conv MFMA A-layout
#define ALS 72   // aL row stride (halfs), 64 rows
#define Y1S 264  // y1L / hL row stride (halfs), 64 rows
#define SLS 68   // sLf row stride (floats)
#define HLS 20   // hidL row stride (floats)

#define MFMA16(a, b, c) __builtin_amdgcn_mfma_f32_16x16x32_f16(a, b, c, 0, 0, 0)

__global__ __launch_bounds__(512, 4) void beat_main(
    const float* __restrict__ x,
    const float* __restrict__ conv_b,
    const float* __restrict__ se_w1, const float* __restrict__ se_b1,
    const float* __restrict__ se_w2, const float* __restrict__ se_b2,
    const float* __restrict__ b1, const float* __restrict__ b2,
    const float* __restrict__ sb,
    const float* __restrict__ wo, const float* __restrict__ bo,
    const half_t* __restrict__ w1p, const half_t* __restrict__ w2p,
    const half_t* __restrict__ swp, const half_t* __restrict__ cwB,
    float* __restrict__ out) {

    __shared__ __align__(16) char smem[58752];
    half_t* xcL = (half_t*)smem;             // 95*72*2 = 13680 -> pad 13696
    half_t* aL  = (half_t*)(smem + 13696);   // 64*72*2 = 9216 -> 22912 (alive thru phase 4)
    char*   U   = smem + 22912;              // 33792-byte phase union
    half_t* xLh = (half_t*)U;                // phase0: 99*32 halfs = 6336
    float*  sLf = (float*)U;                 // phase1: 64*68 floats = 17408
    float*  hidL= (float*)(U + 17408);       // phase1: 64*20 floats = 5120
    half_t* y1L = (half_t*)U;                // phase2+: 64*264 halfs = 33792
    float*  woL = (float*)(smem + 56704);    // 512 floats -> 58752

    const int tid = threadIdx.x;
    const int bi = blockIdx.x;
    const int b = bi >> 6;
    const int t0 = (bi & 63) << 6;
    const int lane = tid & 63, wv = tid >> 6;     // wv in 0..7
    const int quad = lane >> 4, rl = lane & 15;

    // ---- phase 0a: stage x (fp16 pairs, rows zero-padded to 32) + wo ----
    if (tid < 256) ((f2v*)woL)[tid] = ((const f2v*)wo)[tid];   // 512 floats
    for (int idx = tid; idx < 99 * 13; idx += 512) {
        int fi = idx / 13, ip = idx - fi * 13;
        int tx = t0 - 35 + fi;
        h2v v;
        if (tx >= 0) {
            const float* xp = x + ((size_t)(b * 4096 + tx)) * 26 + 2 * ip;
            v[0] = to_h(xp[0]); v[1] = to_h(xp[1]);
        } else { v[0] = (_Float16)0.f; v[1] = (_Float16)0.f; }
        *(h2v*)(xLh + fi * XLS + 2 * ip) = v;
    }
    for (int idx = tid; idx < 99 * 3; idx += 512) {            // zero pad halfs 26..31
        int fi = idx / 3, p = idx - fi * 3;
        h2v z; z[0] = (_Float16)0.f; z[1] = (_Float16)0.f;
        *(h2v*)(xLh + fi * XLS + 26 + 2 * p) = z;
    }
    __syncthreads();

    // ---- phase 0b: conv as MFMA: xc = relu(win(x) @ cw + b), M=96(95) N=64 K=160 ----
    // 24 units (rb 0..5 x nt 0..3), 3 per wave; 5 MFMAs each (k5 = tap row).
    {
        const h8* cwv = (const h8*)cwB;        // frag(k5,nt) = cwv[(k5*4+nt)*64 + lane]
#pragma unroll
        for (int s = 0; s < 3; s++) {
            int u = wv + 8 * s;                // 0..23
            int rb = u >> 2, nt = u & 3;
            f4 acc;
#pragma unroll
            for (int r = 0; r < 4; r++) acc[r] = 0.f;
#pragma unroll
            for (int k5 = 0; k5 < 5; k5++) {
                h8 xv = *(const h8*)(xLh + (rb * 16 + rl + k5) * XLS + quad * 8);
                h8 bf = cwv[(k5 * 4 + nt) * 64 + lane];
                acc = MFMA16(xv, bf, acc);
            }
            int n = nt * 16 + rl;
            float bias = conv_b[n];
#pragma unroll
            for (int r = 0; r < 4; r++) {
                int m = rb * 16 + quad * 4 + r;
                if (m < 95) {
                    int t = t0 - 31 + m;
                    float v = (t >= 0) ? fmaxf(acc[r] + bias, 0.f) : 0.f;
                    xcL[m * XCS + n] = to_h(v);
                }
            }
        }
    }
    __syncthreads();

    // ---- phase 1a: window means s[m][c]; thread = (m, 8-channel group), h8 row reads ----
    {
        int m = tid >> 3, cg = tid & 7;
        const half_t* base = xcL + m * XCS + cg * 8;
        f4 a0, a1;
#pragma unroll
        for (int r = 0; r < 4; r++) { a0[r] = 0.f; a1[r] = 0.f; }
#pragma unroll
        for (int w = 0; w < 32; w++) {
            h8 v = *(const h8*)(base + w * XCS);
#pragma unroll
            for (int q = 0; q < 4; q++) { a0[q] += (float)v[q]; a1[q] += (float)v[4 + q]; }
        }
        float* sp = sLf + m * SLS + cg * 8;
        *(f4*)sp       = a0 * (1.f / 32.f);
        *(f4*)(sp + 4) = a1 * (1.f / 32.f);
    }
    __syncthreads();

    // ---- phase 1b: SE hidden = relu(s @ se_w1 + se_b1), 64 m x 16 h ----
    {
        int m = tid >> 3, hh = (tid & 7) * 2;
        float acc0 = se_b1[hh], acc1 = se_b1[hh + 1];
        for (int c = 0; c < 64; c++) {
            float sv = sLf[m * SLS + c];
            f2v wq = *(const f2v*)(se_w1 + c * 16 + hh);
            acc0 += sv * wq[0]; acc1 += sv * wq[1];
        }
        hidL[m * HLS + hh] = fmaxf(acc0, 0.f);
        hidL[m * HLS + hh + 1] = fmaxf(acc1, 0.f);
    }
    __syncthreads();

    // ---- phase 1c: a = sigmoid(hidden @ se_w2 + se_b2) -> aL (fp16) ----
    {
        int m = tid >> 3, c0 = (tid & 7) * 8;
        float av[8];
#pragma unroll
        for (int j = 0; j < 8; j++) av[j] = se_b2[c0 + j];
        for (int h = 0; h < 16; h++) {
            float hv = hidL[m * HLS + h];
            const f4* wv4 = (const f4*)(se_w2 + h * 64 + c0);
            f4 wq0 = wv4[0], wq1 = wv4[1];
#pragma unroll
            for (int j = 0; j < 4; j++) { av[j] += hv * wq0[j]; av[4 + j] += hv * wq1[j]; }
        }
#pragma unroll
        for (int j = 0; j < 8; j++) {
            float zz = fminf(fmaxf(av[j], -30.f), 30.f);
            float s = 1.f / (1.f + __expf(-zz));
            aL[m * ALS + c0 + j] = to_h(s);
        }
    }
    __syncthreads();

    // ---- phase 2: y1 = relu((a .* window) @ w1 + b1), M=64 K=2048 N=256 ----
    // Wave grid 2M x 4N: wave (wvm,wvn) covers rows wvm*32..+32 (mt 0..1), cols
    // wvn*64..+64 (nt = wvn*4+i). Halves redundant A-reads/gate-muls vs the 8N split.
    // Rolled masked loop + distance-1-pair B prefetch structure preserved.
    const int wvm = wv >> 2, wvn = wv & 3;
    const int mr = wvm * 32;
    {
        h8 avr2[2][2];   // gates for this wave's rows only
#pragma unroll
        for (int mt = 0; mt < 2; mt++)
#pragma unroll
            for (int p = 0; p < 2; p++)
                avr2[mt][p] = *(const h8*)(aL + (mr + mt * 16 + rl) * ALS + p * 32 + quad * 8);

        f4 acc[2][4];
#pragma unroll
        for (int mt = 0; mt < 2; mt++)
#pragma unroll
            for (int i = 0; i < 4; i++)
#pragma unroll
                for (int r = 0; r < 4; r++) acc[mt][i][r] = 0.f;
        const h8* w1v = (const h8*)w1p;
        const int fb = wvn * 4;
        h8 bA[4], bB[4], bC[4], bD[4];
#pragma unroll
        for (int i = 0; i < 4; i++) bA[i] = w1v[(fb + i) * 64 + lane];
#pragma unroll
        for (int i = 0; i < 4; i++) bB[i] = w1v[(16 + fb + i) * 64 + lane];
#pragma unroll 2
        for (int kk = 0; kk < 64; kk += 2) {
            const int k2 = (kk + 2) & 63, k3 = (kk + 3) & 63;  // wrap harmless on last iter
#pragma unroll
            for (int i = 0; i < 4; i++) bC[i] = w1v[(k2 * 16 + fb + i) * 64 + lane];
#pragma unroll
            for (int i = 0; i < 4; i++) bD[i] = w1v[(k3 * 16 + fb + i) * 64 + lane];
            const int wf = kk >> 1;
            {   // even kk: channels 0..31 -> avr2[.][0]
                const int c0 = quad * 8;
#pragma unroll
                for (int mt = 0; mt < 2; mt++) {
                    int m = mr + mt * 16 + rl;
                    h8 xv = *(const h8*)(xcL + (m + wf) * XCS + c0);
                    h8 af = xv * avr2[mt][0];
#pragma unroll
                    for (int i = 0; i < 4; i++)
                        acc[mt][i] = MFMA16(af, bA[i], acc[mt][i]);
                }
            }
            {   // odd kk: channels 32..63 -> avr2[.][1]
                const int c0 = 32 + quad * 8;
#pragma unroll
                for (int mt = 0; mt < 2; mt++) {
                    int m = mr + mt * 16 + rl;
                    h8 xv = *(const h8*)(xcL + (m + wf) * XCS + c0);
                    h8 af = xv * avr2[mt][1];
#pragma unroll
                    for (int i = 0; i < 4; i++)
                        acc[mt][i] = MFMA16(af, bB[i], acc[mt][i]);
                }
            }
#pragma unroll
            for (int i = 0; i < 4; i++) { bA[i] = bC[i]; bB[i] = bD[i]; }
        }
#pragma unroll
        for (int i = 0; i < 4; i++) {
            int n = wvn * 64 + i * 16 + rl;
            float bb = b1[n];
#pragma unroll
            for (int mt = 0; mt < 2; mt++)
#pragma unroll
                for (int r = 0; r < 4; r++) {
                    int m = mr + mt * 16 + quad * 4 + r;
                    y1L[m * Y1S + n] = to_h(fmaxf(acc[mt][i][r] + bb, 0.f));
                }
        }
    }
    __syncthreads();

    // ---- phase 3: h2 = relu(y1 @ w2 + b2), M=64 K=256 N=128; wave wv: cols wv*16..+16 ----
    f4 acc2[4];
#pragma unroll
    for (int mt = 0; mt < 4; mt++)
#pragma unroll
        for (int r = 0; r < 4; r++) acc2[mt][r] = 0.f;
    {
        const h8* w2v = (const h8*)w2p;
        h8 cf = w2v[wv * 64 + lane];
#pragma unroll 2
        for (int kk = 0; kk < 8; kk++) {
            int kn = (kk + 1) & 7;
            h8 nf = w2v[(kn * 8 + wv) * 64 + lane];
#pragma unroll
            for (int mt = 0; mt < 4; mt++) {
                h8 av = *(const h8*)(y1L + (mt * 16 + rl) * Y1S + kk * 32 + quad * 8);
                acc2[mt] = MFMA16(av, cf, acc2[mt]);
            }
            cf = nf;
        }
    }

    // ---- gates reload for phase 4 (aL intact): rows mt*16+rl, all 4 mt ----
    h8 avr[4][2];
#pragma unroll
    for (int mt = 0; mt < 4; mt++)
#pragma unroll
        for (int p = 0; p < 2; p++)
            avr[mt][p] = *(const h8*)(aL + (mt * 16 + rl) * ALS + p * 32 + quad * 8);

    // ---- phase 4: h_short = relu((a .* window[-8:]) @ sw + sb), K=512 N=128 ----
    f4 accS[4];
#pragma unroll
    for (int mt = 0; mt < 4; mt++)
#pragma unroll
        for (int r = 0; r < 4; r++) accS[mt][r] = 0.f;
    {
        const h8* swv = (const h8*)swp;
        h8 cf = swv[wv * 64 + lane];
#pragma unroll 2
        for (int kk = 0; kk < 16; kk++) {
            int kn = (kk + 1) & 15;
            h8 nf = swv[(kn * 8 + wv) * 64 + lane];
            const int wf = 24 + (kk >> 1);
            const int c0 = ((kk & 1) << 5) + quad * 8;
#pragma unroll
            for (int mt = 0; mt < 4; mt++) {
                int m = mt * 16 + rl;
                h8 xv = *(const h8*)(xcL + (m + wf) * XCS + c0);
                h8 af = xv * avr[mt][kk & 1];
                accS[mt] = MFMA16(af, cf, accS[mt]);
            }
            cf = nf;
        }
    }
    __syncthreads();  // phase-3 reads of y1L done before overwrite

    // ---- phase 5a: hL[m][0:128]=relu(h2), hL[m][128:256]=relu(h_short) ----
    {
        int n = wv * 16 + rl;
        float bb2 = b2[n], bbs = sb[n];
#pragma unroll
        for (int mt = 0; mt < 4; mt++)
#pragma unroll
            for (int r = 0; r < 4; r++) {
                int m = mt * 16 + quad * 4 + r;
                y1L[m * Y1S + n]       = to_h(fmaxf(acc2[mt][r] + bb2, 0.f));
                y1L[m * Y1S + 128 + n] = to_h(fmaxf(accS[mt][r] + bbs, 0.f));
            }
    }
    __syncthreads();

    // ---- phase 5b: out = sigmoid(h @ wo + bo), 128 threads ----
    if (tid < 128) {
        int m = tid >> 1, o = tid & 1;
        float z = bo[o];
        const half_t* hrow = y1L + m * Y1S;
        for (int nb = 0; nb < 32; nb++) {
            h8 hv = *(const h8*)(hrow + nb * 8);
#pragma unroll
            for (int q = 0; q < 8; q++)
                z += (float)hv[q] * woL[(nb * 8 + q) * 2 + o];
        }
        z = fminf(fmaxf(z, -30.f), 30.f);
        float sg = 1.f / (1.f + __expf(-z));
        out[((size_t)(b * 4096 + t0 + m)) * 2 + o] = sg;
    }
}

extern "C" void kernel_launch(void* const* d_in, const int* in_sizes, int n_in,
                              void* d_out, int out_size, void* d_ws, size_t ws_size,
                              hipStream_t stream) {
    const float* x      = (const float*)d_in[0];
    const float* conv_w = (const float*)d_in[1];
    const float* conv_b = (const float*)d_in[2];
    const float* se_w1  = (const float*)d_in[3];
    const float* se_b1  = (const float*)d_in[4];
    const float* se_w2  = (const float*)d_in[5];
    const float* se_b2  = (const float*)d_in[6];
    const float* w1     = (const float*)d_in[7];
    const float* b1     = (const float*)d_in[8];
    const float* w2     = (const float*)d_in[9];
    const float* b2     = (const float*)d_in[10];
    const float* sw     = (const float*)d_in[11];
    const float* sb     = (const float*)d_in[12];
    const float* wo     = (const float*)d_in[13];
    const float* bo     = (const float*)d_in[14];
    half_t* wsH = (half_t*)d_ws;

    hipLaunchKernelGGL(pack_k, dim3(337), dim3(256), 0, stream, w1, w2, sw, conv_w, wsH);
    hipLaunchKernelGGL(beat_main, dim3(512), dim3(512), 0, stream,
                       x, conv_b, se_w1, se_b1, se_w2, se_b2, b1, b2, sb, wo, bo,
                       wsH, wsH + 524288, wsH + 557056, wsH + 622592,
                       (float*)d_out);
}

// Round 7
// 139.440 us; speedup vs baseline: 1.0980x; 1.0556x over previous
//
#include <hip/hip_runtime.h>

typedef _Float16 half_t;
typedef __attribute__((ext_vector_type(8))) _Float16 h8;
typedef __attribute__((ext_vector_type(2))) _Float16 h2v;
typedef __attribute__((ext_vector_type(4))) float f4;
typedef __attribute__((ext_vector_type(2))) float f2v;

// fp32 -> fp16 with inf/NaN killing (fmaxf/fminf return the non-NaN operand).
__device__ __forceinline__ half_t to_h(float v) {
    v = fminf(fmaxf(v, -60000.f), 60000.f);
    return (half_t)v;
}

// ---------------- pack kernel: bilaterally-coalesced fp32 -> fp16 MFMA-B frags ----------
// ws layout (half elements):
//   w1p: [0, 524288)          [kk=64][nt=16][lane=64][j=8]
//   w2p: [524288, 557056)     [kk=8][nt=8][64][8]
//   swp: [557056, 622592)     [kk=16][nt=8][64][8]
//   cwB: [622592, 632832)     [k5=5][nt=4][lane=64][j=8]  conv B-frags, taps 26..31 = 0
__global__ void pack_k(const float* __restrict__ w1, const float* __restrict__ w2,
                       const float* __restrict__ sw, const float* __restrict__ cw,
                       half_t* __restrict__ wsH) {
    int i = blockIdx.x * 256 + threadIdx.x;
    if (i < 65536) {                        // w1 [2048][256]: 65536 h8 jobs
        int L = i & 63, nt = (i >> 6) & 15, kk = i >> 10;
        int k0 = kk * 32 + ((L >> 4) << 3), n = (nt << 4) + (L & 15);
        h8 v;
#pragma unroll
        for (int j = 0; j < 8; j++) v[j] = to_h(w1[(k0 + j) * 256 + n]);
        *(h8*)(wsH + ((((kk * 16 + nt) * 64 + L)) << 3)) = v;
    } else if (i < 69632) {                 // w2 [256][128]: 4096 jobs
        int o = i - 65536;
        int L = o & 63, nt = (o >> 6) & 7, kk = o >> 9;
        int k0 = kk * 32 + ((L >> 4) << 3), n = (nt << 4) + (L & 15);
        h8 v;
#pragma unroll
        for (int j = 0; j < 8; j++) v[j] = to_h(w2[(k0 + j) * 128 + n]);
        *(h8*)(wsH + 524288 + ((((kk * 8 + nt) * 64 + L)) << 3)) = v;
    } else if (i < 77824) {                 // sw [512][128]: 8192 jobs
        int o = i - 69632;
        int L = o & 63, nt = (o >> 6) & 7, kk = o >> 9;
        int k0 = kk * 32 + ((L >> 4) << 3), n = (nt << 4) + (L & 15);
        h8 v;
#pragma unroll
        for (int j = 0; j < 8; j++) v[j] = to_h(sw[(k0 + j) * 128 + n]);
        *(h8*)(wsH + 557056 + ((((kk * 8 + nt) * 64 + L)) << 3)) = v;
    } else if (i < 79104) {                 // conv B-frags: 1280 h8 jobs
        int o = i - 77824;
        int L = o & 63, nt = (o >> 6) & 3, k5 = o >> 8;
        int n = nt * 16 + (L & 15);
        h8 v;
#pragma unroll
        for (int j = 0; j < 8; j++) {
            int kin = ((L >> 4) << 3) + j;                  // tap-channel within 32-group
            v[j] = (kin < 26) ? to_h(cw[(k5 * 26 + kin) * 64 + n]) : (half_t)0.f;
        }
        *(h8*)(wsH + 622592 + ((size_t)o << 3)) = v;
    }
}

// ---------------- main fused kernel ----------------
// block = 512 thr (8 waves), one b and 64 consecutive t. Grid = 8*64 = 512.
// POST-MORTEM LEDGER:
//  prev-session R9/R11: 32x32x16 restructure, full K unroll -> lost (stall / spills).
//  R2: P4-into-P2 fusion w/ tail prefetch + in-reg P5 -> ~135 regs > 128 budget,
//      15.6MB spills, +10us. R3: same at (512,2) -> crossed 128-reg occupancy quantum,
//      1 block/CU, +28us.
//  R4: in-register P5 via __shfl_xor -> ds_bpermute = MORE LDS traffic, +3us. LDS P5 kept.
//  R5: 32-row half-tile, grid 1024 -> B-stream x2, MFMA:B ratio halved, +13us.
//  R6: 2Mx4N wave split -> A-reads halved (confirmed) but B L2-traffic x2 (+15us) and
//      x4 B-prefetch broke the 64-VGPR cap. 8-wave N-split is B-traffic-optimal.
// CURRENT (R7): LEAN P4 fusion. Tail 8 kk-pairs of phase 2 (kk 48..63) == phase 4's
// exact A-stream (wf=24+(ks>>1), channel half ks&1), so fuse accS MFMAs there, reusing
// af. Unlike R2: NO tail B-prefetch (pair 48 uses rotated bA/bB free; 50..62 load
// direct) and NO in-reg P5 -> ~110 regs, fits the 128 budget of (512,4).
#define XCS 72   // xcL row stride (halfs), 95 rows, frame f <-> t = t0-31+f
#define XLS 32   // xLh row stride (halfs): 26 data + 6 zero-pad = conv MFMA A-layout
#define ALS 72   // aL row stride (halfs), 64 rows
#define Y1S 264  // y1L / hL row stride (halfs), 64 rows
#define SLS 68   // sLf row stride (floats)
#define HLS 20   // hidL row stride (floats)

#define MFMA16(a, b, c) __builtin_amdgcn_mfma_f32_16x16x32_f16(a, b, c, 0, 0, 0)

// one fused tail kk-pair: phase-2 MFMAs + phase-4 (accS) MFMAs sharing af
#define TAILPAIR(BA0, BA1, BB0, BB1, S0, S1, WF) do {                          \
    {   const int c0e = quad * 8;                                              \
        _Pragma("unroll")                                                      \
        for (int mt = 0; mt < 4; mt++) {                                       \
            int m = mt * 16 + rl;                                              \
            h8 xv = *(const h8*)(xcL + (m + (WF)) * XCS + c0e);                \
            h8 af = xv * avr[mt][0];                                           \
            acc[mt][0] = MFMA16(af, BA0, acc[mt][0]);                          \
            acc[mt][1] = MFMA16(af, BA1, acc[mt][1]);                          \
            accS[mt]   = MFMA16(af, S0, accS[mt]);                             \
        }                                                                      \
    }                                                                          \
    {   const int c0o = 32 + quad * 8;                                         \
        _Pragma("unroll")                                                      \
        for (int mt = 0; mt < 4; mt++) {                                       \
            int m = mt * 16 + rl;                                              \
            h8 xv = *(const h8*)(xcL + (m + (WF)) * XCS + c0o);                \
            h8 af = xv * avr[mt][1];                                           \
            acc[mt][0] = MFMA16(af, BB0, acc[mt][0]);                          \
            acc[mt][1] = MFMA16(af, BB1, acc[mt][1]);                          \
            accS[mt]   = MFMA16(af, S1, accS[mt]);                             \
        }                                                                      \
    }                                                                          \
} while (0)

__global__ __launch_bounds__(512, 4) void beat_main(
    const float* __restrict__ x,
    const float* __restrict__ conv_b,
    const float* __restrict__ se_w1, const float* __restrict__ se_b1,
    const float* __restrict__ se_w2, const float* __restrict__ se_b2,
    const float* __restrict__ b1, const float* __restrict__ b2,
    const float* __restrict__ sb,
    const float* __restrict__ wo, const float* __restrict__ bo,
    const half_t* __restrict__ w1p, const half_t* __restrict__ w2p,
    const half_t* __restrict__ swp, const half_t* __restrict__ cwB,
    float* __restrict__ out) {

    __shared__ __align__(16) char smem[58752];
    half_t* xcL = (half_t*)smem;             // 95*72*2 = 13680 -> pad 13696
    half_t* aL  = (half_t*)(smem + 13696);   // 64*72*2 = 9216 -> 22912
    char*   U   = smem + 22912;              // 33792-byte phase union
    half_t* xLh = (half_t*)U;                // phase0: 99*32 halfs = 6336
    float*  sLf = (float*)U;                 // phase1: 64*68 floats = 17408
    float*  hidL= (float*)(U + 17408);       // phase1: 64*20 floats = 5120
    half_t* y1L = (half_t*)U;                // phase2+: 64*264 halfs = 33792
    float*  woL = (float*)(smem + 56704);    // 512 floats -> 58752

    const int tid = threadIdx.x;
    const int bi = blockIdx.x;
    const int b = bi >> 6;
    const int t0 = (bi & 63) << 6;
    const int lane = tid & 63, wv = tid >> 6;     // wv in 0..7
    const int quad = lane >> 4, rl = lane & 15;

    // ---- phase 0a: stage x (fp16 pairs, rows zero-padded to 32) + wo ----
    if (tid < 256) ((f2v*)woL)[tid] = ((const f2v*)wo)[tid];   // 512 floats
    for (int idx = tid; idx < 99 * 13; idx += 512) {
        int fi = idx / 13, ip = idx - fi * 13;
        int tx = t0 - 35 + fi;
        h2v v;
        if (tx >= 0) {
            const float* xp = x + ((size_t)(b * 4096 + tx)) * 26 + 2 * ip;
            v[0] = to_h(xp[0]); v[1] = to_h(xp[1]);
        } else { v[0] = (_Float16)0.f; v[1] = (_Float16)0.f; }
        *(h2v*)(xLh + fi * XLS + 2 * ip) = v;
    }
    for (int idx = tid; idx < 99 * 3; idx += 512) {            // zero pad halfs 26..31
        int fi = idx / 3, p = idx - fi * 3;
        h2v z; z[0] = (_Float16)0.f; z[1] = (_Float16)0.f;
        *(h2v*)(xLh + fi * XLS + 26 + 2 * p) = z;
    }
    __syncthreads();

    // ---- phase 0b: conv as MFMA: xc = relu(win(x) @ cw + b), M=96(95) N=64 K=160 ----
    {
        const h8* cwv = (const h8*)cwB;        // frag(k5,nt) = cwv[(k5*4+nt)*64 + lane]
#pragma unroll
        for (int s = 0; s < 3; s++) {
            int u = wv + 8 * s;                // 0..23
            int rb = u >> 2, nt = u & 3;
            f4 acc;
#pragma unroll
            for (int r = 0; r < 4; r++) acc[r] = 0.f;
#pragma unroll
            for (int k5 = 0; k5 < 5; k5++) {
                h8 xv = *(const h8*)(xLh + (rb * 16 + rl + k5) * XLS + quad * 8);
                h8 bf = cwv[(k5 * 4 + nt) * 64 + lane];
                acc = MFMA16(xv, bf, acc);
            }
            int n = nt * 16 + rl;
            float bias = conv_b[n];
#pragma unroll
            for (int r = 0; r < 4; r++) {
                int m = rb * 16 + quad * 4 + r;
                if (m < 95) {
                    int t = t0 - 31 + m;
                    float v = (t >= 0) ? fmaxf(acc[r] + bias, 0.f) : 0.f;
                    xcL[m * XCS + n] = to_h(v);
                }
            }
        }
    }
    __syncthreads();

    // ---- phase 1a: window means s[m][c]; thread = (m, 8-channel group), h8 row reads ----
    {
        int m = tid >> 3, cg = tid & 7;
        const half_t* base = xcL + m * XCS + cg * 8;
        f4 a0, a1;
#pragma unroll
        for (int r = 0; r < 4; r++) { a0[r] = 0.f; a1[r] = 0.f; }
#pragma unroll
        for (int w = 0; w < 32; w++) {
            h8 v = *(const h8*)(base + w * XCS);
#pragma unroll
            for (int q = 0; q < 4; q++) { a0[q] += (float)v[q]; a1[q] += (float)v[4 + q]; }
        }
        float* sp = sLf + m * SLS + cg * 8;
        *(f4*)sp       = a0 * (1.f / 32.f);
        *(f4*)(sp + 4) = a1 * (1.f / 32.f);
    }
    __syncthreads();

    // ---- phase 1b: SE hidden = relu(s @ se_w1 + se_b1), 64 m x 16 h ----
    {
        int m = tid >> 3, hh = (tid & 7) * 2;
        float acc0 = se_b1[hh], acc1 = se_b1[hh + 1];
        for (int c = 0; c < 64; c++) {
            float sv = sLf[m * SLS + c];
            f2v wq = *(const f2v*)(se_w1 + c * 16 + hh);
            acc0 += sv * wq[0]; acc1 += sv * wq[1];
        }
        hidL[m * HLS + hh] = fmaxf(acc0, 0.f);
        hidL[m * HLS + hh + 1] = fmaxf(acc1, 0.f);
    }
    __syncthreads();

    // ---- phase 1c: a = sigmoid(hidden @ se_w2 + se_b2) -> aL (fp16) ----
    {
        int m = tid >> 3, c0 = (tid & 7) * 8;
        float av[8];
#pragma unroll
        for (int j = 0; j < 8; j++) av[j] = se_b2[c0 + j];
        for (int h = 0; h < 16; h++) {
            float hv = hidL[m * HLS + h];
            const f4* wv4 = (const f4*)(se_w2 + h * 64 + c0);
            f4 wq0 = wv4[0], wq1 = wv4[1];
#pragma unroll
            for (int j = 0; j < 4; j++) { av[j] += hv * wq0[j]; av[4 + j] += hv * wq1[j]; }
        }
#pragma unroll
        for (int j = 0; j < 8; j++) {
            float zz = fminf(fmaxf(av[j], -30.f), 30.f);
            float s = 1.f / (1.f + __expf(-zz));
            aL[m * ALS + c0 + j] = to_h(s);
        }
    }
    __syncthreads();

    // ---- gates into registers: avr[mt][half], rows mt*16+rl, channels half*32+quad*8 ----
    h8 avr[4][2];
#pragma unroll
    for (int mt = 0; mt < 4; mt++)
#pragma unroll
        for (int p = 0; p < 2; p++)
            avr[mt][p] = *(const h8*)(aL + (mt * 16 + rl) * ALS + p * 32 + quad * 8);

    // ---- phase 2 (+ lean-fused former phase 4): y1 = relu((a .* win) @ w1 + b1),
    //      M=64 K=2048 N=256; h_short partials accS ride the kk in [48,64) A-stream.
    f4 accS[4];
#pragma unroll
    for (int mt = 0; mt < 4; mt++)
#pragma unroll
        for (int r = 0; r < 4; r++) accS[mt][r] = 0.f;
    {
        f4 acc[4][2];
#pragma unroll
        for (int mt = 0; mt < 4; mt++)
#pragma unroll
            for (int i = 0; i < 2; i++)
#pragma unroll
                for (int r = 0; r < 4; r++) acc[mt][i][r] = 0.f;
        const h8* w1v = (const h8*)w1p;
        const h8* swv = (const h8*)swp;
        const int fb = wv * 2;
        h8 bA[2], bB[2], bC[2], bD[2];
#pragma unroll
        for (int i = 0; i < 2; i++) bA[i] = w1v[(fb + i) * 64 + lane];
#pragma unroll
        for (int i = 0; i < 2; i++) bB[i] = w1v[(16 + fb + i) * 64 + lane];
        // main 24 pairs: byte-identical to the 62.4us empirical optimum
#pragma unroll 2
        for (int kk = 0; kk < 48; kk += 2) {
            const int k2 = kk + 2, k3 = kk + 3;
#pragma unroll
            for (int i = 0; i < 2; i++) bC[i] = w1v[(k2 * 16 + fb + i) * 64 + lane];
#pragma unroll
            for (int i = 0; i < 2; i++) bD[i] = w1v[(k3 * 16 + fb + i) * 64 + lane];
            const int wf = kk >> 1;
            {   // even kk: channels 0..31 -> avr[.][0]
                const int c0 = quad * 8;
#pragma unroll
                for (int mt = 0; mt < 4; mt++) {
                    int m = mt * 16 + rl;
                    h8 xv = *(const h8*)(xcL + (m + wf) * XCS + c0);
                    h8 af = xv * avr[mt][0];
                    acc[mt][0] = MFMA16(af, bA[0], acc[mt][0]);
                    acc[mt][1] = MFMA16(af, bA[1], acc[mt][1]);
                }
            }
            {   // odd kk: channels 32..63 -> avr[.][1]
                const int c0 = 32 + quad * 8;
#pragma unroll
                for (int mt = 0; mt < 4; mt++) {
                    int m = mt * 16 + rl;
                    h8 xv = *(const h8*)(xcL + (m + wf) * XCS + c0);
                    h8 af = xv * avr[mt][1];
                    acc[mt][0] = MFMA16(af, bB[0], acc[mt][0]);
                    acc[mt][1] = MFMA16(af, bB[1], acc[mt][1]);
                }
            }
#pragma unroll
            for (int i = 0; i < 2; i++) { bA[i] = bC[i]; bB[i] = bD[i]; }
        }
        // fused tail, pair kk=48/49: B-frags already in bA/bB from the last rotation
        {
            h8 s0 = swv[(0 * 8 + wv) * 64 + lane];
            h8 s1 = swv[(1 * 8 + wv) * 64 + lane];
            TAILPAIR(bA[0], bA[1], bB[0], bB[1], s0, s1, 24);
        }
        // fused tail, pairs kk=50..62: B loaded direct (no prefetch regs -> fits cap)
#pragma unroll 2
        for (int kk = 50; kk < 64; kk += 2) {
            h8 tA0 = w1v[(kk * 16 + fb) * 64 + lane];
            h8 tA1 = w1v[(kk * 16 + fb + 1) * 64 + lane];
            h8 tB0 = w1v[((kk + 1) * 16 + fb) * 64 + lane];
            h8 tB1 = w1v[((kk + 1) * 16 + fb + 1) * 64 + lane];
            const int ks = kk - 48;
            h8 s0 = swv[(ks * 8 + wv) * 64 + lane];
            h8 s1 = swv[((ks + 1) * 8 + wv) * 64 + lane];
            TAILPAIR(tA0, tA1, tB0, tB1, s0, s1, kk >> 1);
        }
#pragma unroll
        for (int i = 0; i < 2; i++) {
            int n = wv * 32 + i * 16 + rl;
            float bb = b1[n];
#pragma unroll
            for (int mt = 0; mt < 4; mt++)
#pragma unroll
                for (int r = 0; r < 4; r++) {
                    int m = mt * 16 + quad * 4 + r;
                    y1L[m * Y1S + n] = to_h(fmaxf(acc[mt][i][r] + bb, 0.f));
                }
        }
    }
    __syncthreads();

    // ---- phase 3: h2 = relu(y1 @ w2 + b2), M=64 K=256 N=128; wave wv: cols wv*16..+16 ----
    f4 acc2[4];
#pragma unroll
    for (int mt = 0; mt < 4; mt++)
#pragma unroll
        for (int r = 0; r < 4; r++) acc2[mt][r] = 0.f;
    {
        const h8* w2v = (const h8*)w2p;
        h8 cf = w2v[wv * 64 + lane];
#pragma unroll 2
        for (int kk = 0; kk < 8; kk++) {
            int kn = (kk + 1) & 7;
            h8 nf = w2v[(kn * 8 + wv) * 64 + lane];
#pragma unroll
            for (int mt = 0; mt < 4; mt++) {
                h8 av = *(const h8*)(y1L + (mt * 16 + rl) * Y1S + kk * 32 + quad * 8);
                acc2[mt] = MFMA16(av, cf, acc2[mt]);
            }
            cf = nf;
        }
    }
    __syncthreads();  // phase-3 reads of y1L done before overwrite

    // ---- phase 5a: hL[m][0:128]=relu(h2), hL[m][128:256]=relu(h_short) ----
    {
        int n = wv * 16 + rl;
        float bb2 = b2[n], bbs = sb[n];
#pragma unroll
        for (int mt = 0; mt < 4; mt++)
#pragma unroll
            for (int r = 0; r < 4; r++) {
                int m = mt * 16 + quad * 4 + r;
                y1L[m * Y1S + n]       = to_h(fmaxf(acc2[mt][r] + bb2, 0.f));
                y1L[m * Y1S + 128 + n] = to_h(fmaxf(accS[mt][r] + bbs, 0.f));
            }
    }
    __syncthreads();

    // ---- phase 5b: out = sigmoid(h @ wo + bo), 128 threads ----
    if (tid < 128) {
        int m = tid >> 1, o = tid & 1;
        float z = bo[o];
        const half_t* hrow = y1L + m * Y1S;
        for (int nb = 0; nb < 32; nb++) {
            h8 hv = *(const h8*)(hrow + nb * 8);
#pragma unroll
            for (int q = 0; q < 8; q++)
                z += (float)hv[q] * woL[(nb * 8 + q) * 2 + o];
        }
        z = fminf(fmaxf(z, -30.f), 30.f);
        float sg = 1.f / (1.f + __expf(-z));
        out[((size_t)(b * 4096 + t0 + m)) * 2 + o] = sg;
    }
}

extern "C" void kernel_launch(void* const* d_in, const int* in_sizes, int n_in,
                              void* d_out, int out_size, void* d_ws, size_t ws_size,
                              hipStream_t stream) {
    const float* x      = (const float*)d_in[0];
    const float* conv_w = (const float*)d_in[1];
    const float* conv_b = (const float*)d_in[2];
    const float* se_w1  = (const float*)d_in[3];
    const float* se_b1  = (const float*)d_in[4];
    const float* se_w2  = (const float*)d_in[5];
    const float* se_b2  = (const float*)d_in[6];
    const float* w1     = (const float*)d_in[7];
    const float* b1     = (const float*)d_in[8];
    const float* w2     = (const float*)d_in[9];
    const float* b2     = (const float*)d_in[10];
    const float* sw     = (const float*)d_in[11];
    const float* sb     = (const float*)d_in[12];
    const float* wo     = (const float*)d_in[13];
    const float* bo     = (const float*)d_in[14];
    half_t* wsH = (half_t*)d_ws;

    hipLaunchKernelGGL(pack_k, dim3(337), dim3(256), 0, stream, w1, w2, sw, conv_w, wsH);
    hipLaunchKernelGGL(beat_main, dim3(512), dim3(512), 0, stream,
                       x, conv_b, se_w1, se_b1, se_w2, se_b2, b1, b2, sb, wo, bo,
                       wsH, wsH + 524288, wsH + 557056, wsH + 622592,
                       (float*)d_out);
}

// Round 8
// 138.142 us; speedup vs baseline: 1.1083x; 1.0094x over previous
//
#include <hip/hip_runtime.h>

typedef _Float16 half_t;
typedef __attribute__((ext_vector_type(8))) _Float16 h8;
typedef __attribute__((ext_vector_type(2))) _Float16 h2v;
typedef __attribute__((ext_vector_type(4))) float f4;
typedef __attribute__((ext_vector_type(2))) float f2v;

// fp32 -> fp16 with inf/NaN killing (fmaxf/fminf return the non-NaN operand).
__device__ __forceinline__ half_t to_h(float v) {
    v = fminf(fmaxf(v, -60000.f), 60000.f);
    return (half_t)v;
}

// ---------------- pack kernel: bilaterally-coalesced fp32 -> fp16 MFMA-B frags ----------
// ws layout (half elements):
//   w1p: [0, 524288)          [kk=64][nt=16][lane=64][j=8]
//   w2p: [524288, 557056)     [kk=8][nt=8][64][8]
//   swp: [557056, 622592)     [kk=16][nt=8][64][8]
//   cwB: [622592, 632832)     [k5=5][nt=4][lane=64][j=8]  conv B-frags, taps 26..31 = 0
//   wop: [632832, 636928)     [kk=8][lane=64][j=8]        out-GEMV B-frags, cols 2..15 = 0
__global__ void pack_k(const float* __restrict__ w1, const float* __restrict__ w2,
                       const float* __restrict__ sw, const float* __restrict__ cw,
                       const float* __restrict__ wo, half_t* __restrict__ wsH) {
    int i = blockIdx.x * 256 + threadIdx.x;
    if (i < 65536) {                        // w1 [2048][256]: 65536 h8 jobs
        int L = i & 63, nt = (i >> 6) & 15, kk = i >> 10;
        int k0 = kk * 32 + ((L >> 4) << 3), n = (nt << 4) + (L & 15);
        h8 v;
#pragma unroll
        for (int j = 0; j < 8; j++) v[j] = to_h(w1[(k0 + j) * 256 + n]);
        *(h8*)(wsH + ((((kk * 16 + nt) * 64 + L)) << 3)) = v;
    } else if (i < 69632) {                 // w2 [256][128]: 4096 jobs
        int o = i - 65536;
        int L = o & 63, nt = (o >> 6) & 7, kk = o >> 9;
        int k0 = kk * 32 + ((L >> 4) << 3), n = (nt << 4) + (L & 15);
        h8 v;
#pragma unroll
        for (int j = 0; j < 8; j++) v[j] = to_h(w2[(k0 + j) * 128 + n]);
        *(h8*)(wsH + 524288 + ((((kk * 8 + nt) * 64 + L)) << 3)) = v;
    } else if (i < 77824) {                 // sw [512][128]: 8192 jobs
        int o = i - 69632;
        int L = o & 63, nt = (o >> 6) & 7, kk = o >> 9;
        int k0 = kk * 32 + ((L >> 4) << 3), n = (nt << 4) + (L & 15);
        h8 v;
#pragma unroll
        for (int j = 0; j < 8; j++) v[j] = to_h(sw[(k0 + j) * 128 + n]);
        *(h8*)(wsH + 557056 + ((((kk * 8 + nt) * 64 + L)) << 3)) = v;
    } else if (i < 79104) {                 // conv B-frags: 1280 h8 jobs
        int o = i - 77824;
        int L = o & 63, nt = (o >> 6) & 3, k5 = o >> 8;
        int n = nt * 16 + (L & 15);
        h8 v;
#pragma unroll
        for (int j = 0; j < 8; j++) {
            int kin = ((L >> 4) << 3) + j;                  // tap-channel within 32-group
            v[j] = (kin < 26) ? to_h(cw[(k5 * 26 + kin) * 64 + n]) : (half_t)0.f;
        }
        *(h8*)(wsH + 622592 + ((size_t)o << 3)) = v;
    } else if (i < 79616) {                 // wop: out-GEMV B-frags, 512 h8 jobs
        int o = i - 79104;
        int L = o & 63, kk = o >> 6;
        int n = L & 15;
        h8 v;
#pragma unroll
        for (int j = 0; j < 8; j++) {
            int k = kk * 32 + ((L >> 4) << 3) + j;
            v[j] = (n < 2) ? to_h(wo[k * 2 + n]) : (half_t)0.f;
        }
        *(h8*)(wsH + 632832 + ((size_t)o << 3)) = v;
    }
}

// ---------------- main fused kernel ----------------
// block = 512 thr (8 waves), one b and 64 consecutive t. Grid = 8*64 = 512.
// POST-MORTEM LEDGER:
//  prev-session R9/R11: 32x32x16 restructure, full K unroll -> lost (stall / spills).
//  R2/R7: P4-into-P2 fusion (both variants) -> accS's 16 AGPRs live through phase-2's
//      128-reg peak -> spills (15.6 / 5.4 MB). R3: cap-128 -> occupancy halved. The
//      design sits EXACTLY at the 128-total-reg / 4-wave-per-SIMD quantum: any phase
//      overlap that extends accumulator liveness into P2 is structurally dead.
//  R4: in-register P5 via __shfl_xor -> ds_bpermute = MORE LDS traffic, +3us.
//  R5: 32-row half-tile -> B-stream x2, MFMA:B ratio halved, +13us.
//  R6: 2Mx4N wave split -> A-reads halved (confirmed via conflicts) but B L2 x2, +8us.
//      8-wave N-split with full-M per wave is B-traffic-optimal at this tile.
//  Bank conflicts ~4cy/ds_read_b128 = wave64 b128 floor (1024B/128B-per-clk), not fixable.
// CURRENT (R8): R0 base + (1) s_setprio around MFMA clusters (T5 probe), (2) MFMA-ized
// phase 5b via packed wo B-frags (kills the 128-thread serial GEMV + woL stage).
#define XCS 72   // xcL row stride (halfs), 95 rows, frame f <-> t = t0-31+f
#define XLS 32   // xLh row stride (halfs): 26 data + 6 zero-pad = conv MFMA A-layout
#define ALS 72   // aL row stride (halfs), 64 rows
#define Y1S 264  // y1L / hL row stride (halfs), 64 rows
#define SLS 68   // sLf row stride (floats)
#define HLS 20   // hidL row stride (floats)

#define MFMA16(a, b, c) __builtin_amdgcn_mfma_f32_16x16x32_f16(a, b, c, 0, 0, 0)

__global__ __launch_bounds__(512, 4) void beat_main(
    const float* __restrict__ x,
    const float* __restrict__ conv_b,
    const float* __restrict__ se_w1, const float* __restrict__ se_b1,
    const float* __restrict__ se_w2, const float* __restrict__ se_b2,
    const float* __restrict__ b1, const float* __restrict__ b2,
    const float* __restrict__ sb,
    const float* __restrict__ bo,
    const half_t* __restrict__ w1p, const half_t* __restrict__ w2p,
    const half_t* __restrict__ swp, const half_t* __restrict__ cwB,
    const half_t* __restrict__ wop,
    float* __restrict__ out) {

    __shared__ __align__(16) char smem[56704];
    half_t* xcL = (half_t*)smem;             // 95*72*2 = 13680 -> pad 13696
    half_t* aL  = (half_t*)(smem + 13696);   // 64*72*2 = 9216 -> 22912
    char*   U   = smem + 22912;              // 33792-byte phase union
    half_t* xLh = (half_t*)U;                // phase0: 99*32 halfs = 6336
    float*  sLf = (float*)U;                 // phase1: 64*68 floats = 17408
    float*  hidL= (float*)(U + 17408);       // phase1: 64*20 floats = 5120
    half_t* y1L = (half_t*)U;                // phase2+: 64*264 halfs = 33792

    const int tid = threadIdx.x;
    const int bi = blockIdx.x;
    const int b = bi >> 6;
    const int t0 = (bi & 63) << 6;
    const int lane = tid & 63, wv = tid >> 6;     // wv in 0..7
    const int quad = lane >> 4, rl = lane & 15;

    // ---- phase 0a: stage x (fp16 pairs, rows zero-padded to 32) ----
    for (int idx = tid; idx < 99 * 13; idx += 512) {
        int fi = idx / 13, ip = idx - fi * 13;
        int tx = t0 - 35 + fi;
        h2v v;
        if (tx >= 0) {
            const float* xp = x + ((size_t)(b * 4096 + tx)) * 26 + 2 * ip;
            v[0] = to_h(xp[0]); v[1] = to_h(xp[1]);
        } else { v[0] = (_Float16)0.f; v[1] = (_Float16)0.f; }
        *(h2v*)(xLh + fi * XLS + 2 * ip) = v;
    }
    for (int idx = tid; idx < 99 * 3; idx += 512) {            // zero pad halfs 26..31
        int fi = idx / 3, p = idx - fi * 3;
        h2v z; z[0] = (_Float16)0.f; z[1] = (_Float16)0.f;
        *(h2v*)(xLh + fi * XLS + 26 + 2 * p) = z;
    }
    __syncthreads();

    // ---- phase 0b: conv as MFMA: xc = relu(win(x) @ cw + b), M=96(95) N=64 K=160 ----
    {
        const h8* cwv = (const h8*)cwB;        // frag(k5,nt) = cwv[(k5*4+nt)*64 + lane]
#pragma unroll
        for (int s = 0; s < 3; s++) {
            int u = wv + 8 * s;                // 0..23
            int rb = u >> 2, nt = u & 3;
            f4 acc;
#pragma unroll
            for (int r = 0; r < 4; r++) acc[r] = 0.f;
#pragma unroll
            for (int k5 = 0; k5 < 5; k5++) {
                h8 xv = *(const h8*)(xLh + (rb * 16 + rl + k5) * XLS + quad * 8);
                h8 bf = cwv[(k5 * 4 + nt) * 64 + lane];
                acc = MFMA16(xv, bf, acc);
            }
            int n = nt * 16 + rl;
            float bias = conv_b[n];
#pragma unroll
            for (int r = 0; r < 4; r++) {
                int m = rb * 16 + quad * 4 + r;
                if (m < 95) {
                    int t = t0 - 31 + m;
                    float v = (t >= 0) ? fmaxf(acc[r] + bias, 0.f) : 0.f;
                    xcL[m * XCS + n] = to_h(v);
                }
            }
        }
    }
    __syncthreads();

    // ---- phase 1a: window means s[m][c]; thread = (m, 8-channel group), h8 row reads ----
    {
        int m = tid >> 3, cg = tid & 7;
        const half_t* base = xcL + m * XCS + cg * 8;
        f4 a0, a1;
#pragma unroll
        for (int r = 0; r < 4; r++) { a0[r] = 0.f; a1[r] = 0.f; }
#pragma unroll
        for (int w = 0; w < 32; w++) {
            h8 v = *(const h8*)(base + w * XCS);
#pragma unroll
            for (int q = 0; q < 4; q++) { a0[q] += (float)v[q]; a1[q] += (float)v[4 + q]; }
        }
        float* sp = sLf + m * SLS + cg * 8;
        *(f4*)sp       = a0 * (1.f / 32.f);
        *(f4*)(sp + 4) = a1 * (1.f / 32.f);
    }
    __syncthreads();

    // ---- phase 1b: SE hidden = relu(s @ se_w1 + se_b1), 64 m x 16 h ----
    {
        int m = tid >> 3, hh = (tid & 7) * 2;
        float acc0 = se_b1[hh], acc1 = se_b1[hh + 1];
        for (int c = 0; c < 64; c++) {
            float sv = sLf[m * SLS + c];
            f2v wq = *(const f2v*)(se_w1 + c * 16 + hh);
            acc0 += sv * wq[0]; acc1 += sv * wq[1];
        }
        hidL[m * HLS + hh] = fmaxf(acc0, 0.f);
        hidL[m * HLS + hh + 1] = fmaxf(acc1, 0.f);
    }
    __syncthreads();

    // ---- phase 1c: a = sigmoid(hidden @ se_w2 + se_b2) -> aL (fp16) ----
    {
        int m = tid >> 3, c0 = (tid & 7) * 8;
        float av[8];
#pragma unroll
        for (int j = 0; j < 8; j++) av[j] = se_b2[c0 + j];
        for (int h = 0; h < 16; h++) {
            float hv = hidL[m * HLS + h];
            const f4* wv4 = (const f4*)(se_w2 + h * 64 + c0);
            f4 wq0 = wv4[0], wq1 = wv4[1];
#pragma unroll
            for (int j = 0; j < 4; j++) { av[j] += hv * wq0[j]; av[4 + j] += hv * wq1[j]; }
        }
#pragma unroll
        for (int j = 0; j < 8; j++) {
            float zz = fminf(fmaxf(av[j], -30.f), 30.f);
            float s = 1.f / (1.f + __expf(-zz));
            aL[m * ALS + c0 + j] = to_h(s);
        }
    }
    __syncthreads();

    // ---- gates into registers: avr[mt][half], rows mt*16+rl, channels half*32+quad*8 ----
    h8 avr[4][2];
#pragma unroll
    for (int mt = 0; mt < 4; mt++)
#pragma unroll
        for (int p = 0; p < 2; p++)
            avr[mt][p] = *(const h8*)(aL + (mt * 16 + rl) * ALS + p * 32 + quad * 8);

    // ---- phase 2: y1 = relu((a .* window) @ w1 + b1), M=64 K=2048 N=256 ----
    // wave wv: all 64 rows, cols wv*32..+32 (nt = wv*2+i). Prefetch distance 2 kk-steps.
    {
        f4 acc[4][2];
#pragma unroll
        for (int mt = 0; mt < 4; mt++)
#pragma unroll
            for (int i = 0; i < 2; i++)
#pragma unroll
                for (int r = 0; r < 4; r++) acc[mt][i][r] = 0.f;
        const h8* w1v = (const h8*)w1p;
        const int fb = wv * 2;
        h8 bA[2], bB[2], bC[2], bD[2];
#pragma unroll
        for (int i = 0; i < 2; i++) bA[i] = w1v[(fb + i) * 64 + lane];
#pragma unroll
        for (int i = 0; i < 2; i++) bB[i] = w1v[(16 + fb + i) * 64 + lane];
#pragma unroll 2
        for (int kk = 0; kk < 64; kk += 2) {
            const int k2 = (kk + 2) & 63, k3 = (kk + 3) & 63;  // wrap harmless on last iter
#pragma unroll
            for (int i = 0; i < 2; i++) bC[i] = w1v[(k2 * 16 + fb + i) * 64 + lane];
#pragma unroll
            for (int i = 0; i < 2; i++) bD[i] = w1v[(k3 * 16 + fb + i) * 64 + lane];
            const int wf = kk >> 1;
            {   // even kk: channels 0..31 -> avr[.][0]
                const int c0 = quad * 8;
                __builtin_amdgcn_s_setprio(1);
#pragma unroll
                for (int mt = 0; mt < 4; mt++) {
                    int m = mt * 16 + rl;
                    h8 xv = *(const h8*)(xcL + (m + wf) * XCS + c0);
                    h8 af = xv * avr[mt][0];
                    acc[mt][0] = MFMA16(af, bA[0], acc[mt][0]);
                    acc[mt][1] = MFMA16(af, bA[1], acc[mt][1]);
                }
                __builtin_amdgcn_s_setprio(0);
            }
            {   // odd kk: channels 32..63 -> avr[.][1]
                const int c0 = 32 + quad * 8;
                __builtin_amdgcn_s_setprio(1);
#pragma unroll
                for (int mt = 0; mt < 4; mt++) {
                    int m = mt * 16 + rl;
                    h8 xv = *(const h8*)(xcL + (m + wf) * XCS + c0);
                    h8 af = xv * avr[mt][1];
                    acc[mt][0] = MFMA16(af, bB[0], acc[mt][0]);
                    acc[mt][1] = MFMA16(af, bB[1], acc[mt][1]);
                }
                __builtin_amdgcn_s_setprio(0);
            }
#pragma unroll
            for (int i = 0; i < 2; i++) { bA[i] = bC[i]; bB[i] = bD[i]; }
        }
#pragma unroll
        for (int i = 0; i < 2; i++) {
            int n = wv * 32 + i * 16 + rl;
            float bb = b1[n];
#pragma unroll
            for (int mt = 0; mt < 4; mt++)
#pragma unroll
                for (int r = 0; r < 4; r++) {
                    int m = mt * 16 + quad * 4 + r;
                    y1L[m * Y1S + n] = to_h(fmaxf(acc[mt][i][r] + bb, 0.f));
                }
        }
    }
    __syncthreads();

    // ---- phase 3: h2 = relu(y1 @ w2 + b2), M=64 K=256 N=128; wave wv: cols wv*16..+16 ----
    f4 acc2[4];
#pragma unroll
    for (int mt = 0; mt < 4; mt++)
#pragma unroll
        for (int r = 0; r < 4; r++) acc2[mt][r] = 0.f;
    {
        const h8* w2v = (const h8*)w2p;
        h8 cf = w2v[wv * 64 + lane];
#pragma unroll 2
        for (int kk = 0; kk < 8; kk++) {
            int kn = (kk + 1) & 7;
            h8 nf = w2v[(kn * 8 + wv) * 64 + lane];
            __builtin_amdgcn_s_setprio(1);
#pragma unroll
            for (int mt = 0; mt < 4; mt++) {
                h8 av = *(const h8*)(y1L + (mt * 16 + rl) * Y1S + kk * 32 + quad * 8);
                acc2[mt] = MFMA16(av, cf, acc2[mt]);
            }
            __builtin_amdgcn_s_setprio(0);
            cf = nf;
        }
    }

    // ---- phase 4: h_short = relu((a .* window[-8:]) @ sw + sb), K=512 N=128 ----
    f4 accS[4];
#pragma unroll
    for (int mt = 0; mt < 4; mt++)
#pragma unroll
        for (int r = 0; r < 4; r++) accS[mt][r] = 0.f;
    {
        const h8* swv = (const h8*)swp;
        h8 cf = swv[wv * 64 + lane];
#pragma unroll 2
        for (int kk = 0; kk < 16; kk++) {
            int kn = (kk + 1) & 15;
            h8 nf = swv[(kn * 8 + wv) * 64 + lane];
            const int wf = 24 + (kk >> 1);
            const int c0 = ((kk & 1) << 5) + quad * 8;
            __builtin_amdgcn_s_setprio(1);
#pragma unroll
            for (int mt = 0; mt < 4; mt++) {
                int m = mt * 16 + rl;
                h8 xv = *(const h8*)(xcL + (m + wf) * XCS + c0);
                h8 af = xv * avr[mt][kk & 1];
                accS[mt] = MFMA16(af, cf, accS[mt]);
            }
            __builtin_amdgcn_s_setprio(0);
            cf = nf;
        }
    }
    __syncthreads();  // phase-3 reads of y1L done before overwrite

    // ---- phase 5a: hL[m][0:128]=relu(h2), hL[m][128:256]=relu(h_short) ----
    {
        int n = wv * 16 + rl;
        float bb2 = b2[n], bbs = sb[n];
#pragma unroll
        for (int mt = 0; mt < 4; mt++)
#pragma unroll
            for (int r = 0; r < 4; r++) {
                int m = mt * 16 + quad * 4 + r;
                y1L[m * Y1S + n]       = to_h(fmaxf(acc2[mt][r] + bb2, 0.f));
                y1L[m * Y1S + 128 + n] = to_h(fmaxf(accS[mt][r] + bbs, 0.f));
            }
    }
    __syncthreads();

    // ---- phase 5b (MFMA): out = sigmoid(h @ wo_frags + bo); waves 0..3, mt=wv ----
    // A-read pattern identical to phase 3; B = wop (cols 2..15 zero). C: row=quad*4+r,
    // col=rl -> lanes rl<2 write out[m][rl].
    if (wv < 4) {
        const h8* wov = (const h8*)wop;
        f4 accO;
#pragma unroll
        for (int r = 0; r < 4; r++) accO[r] = 0.f;
#pragma unroll
        for (int kk = 0; kk < 8; kk++) {
            h8 av = *(const h8*)(y1L + (wv * 16 + rl) * Y1S + kk * 32 + quad * 8);
            h8 bf = wov[kk * 64 + lane];
            accO = MFMA16(av, bf, accO);
        }
        if (rl < 2) {
            float bb = bo[rl];
#pragma unroll
            for (int r = 0; r < 4; r++) {
                int m = wv * 16 + quad * 4 + r;
                float z = fminf(fmaxf(accO[r] + bb, -30.f), 30.f);
                float sg = 1.f / (1.f + __expf(-z));
                out[((size_t)(b * 4096 + t0 + m)) * 2 + rl] = sg;
            }
        }
    }
}

extern "C" void kernel_launch(void* const* d_in, const int* in_sizes, int n_in,
                              void* d_out, int out_size, void* d_ws, size_t ws_size,
                              hipStream_t stream) {
    const float* x      = (const float*)d_in[0];
    const float* conv_w = (const float*)d_in[1];
    const float* conv_b = (const float*)d_in[2];
    const float* se_w1  = (const float*)d_in[3];
    const float* se_b1  = (const float*)d_in[4];
    const float* se_w2  = (const float*)d_in[5];
    const float* se_b2  = (const float*)d_in[6];
    const float* w1     = (const float*)d_in[7];
    const float* b1     = (const float*)d_in[8];
    const float* w2     = (const float*)d_in[9];
    const float* b2     = (const float*)d_in[10];
    const float* sw     = (const float*)d_in[11];
    const float* sb     = (const float*)d_in[12];
    const float* wo     = (const float*)d_in[13];
    const float* bo     = (const float*)d_in[14];
    half_t* wsH = (half_t*)d_ws;

    hipLaunchKernelGGL(pack_k, dim3(337), dim3(256), 0, stream, w1, w2, sw, conv_w, wo, wsH);
    hipLaunchKernelGGL(beat_main, dim3(512), dim3(512), 0, stream,
                       x, conv_b, se_w1, se_b1, se_w2, se_b2, b1, b2, sb, bo,
                       wsH, wsH + 524288, wsH + 557056, wsH + 622592, wsH + 632832,
                       (float*)d_out);
}